// Round 4
// baseline (7699.867 us; speedup 1.0000x reference)
//
#include <hip/hip_runtime.h>

typedef unsigned short u16;
typedef unsigned int   u32;
typedef _Float16 f16;
typedef _Float16 half2v __attribute__((ext_vector_type(2)));
typedef _Float16 half8v __attribute__((ext_vector_type(8)));
typedef float float4v __attribute__((ext_vector_type(4)));

#define B_  256
#define T_  512
#define I_  64
#define H_  256
#define G_  1024   // 4*H
#define BT_ (B_*T_)

// Pin a 16B quad into AGPRs / read it back. Tied "0" forces the copy.
#define AG_PIN(dst, src) asm volatile("" : "=a"(dst) : "0"(src))
#define AG_GET(dst, src) asm volatile("" : "=v"(dst) : "0"(src))

static __device__ __forceinline__ float fdot2u(u32 a, u32 b, float c) {
#if defined(__has_builtin) && __has_builtin(__builtin_amdgcn_fdot2)
  return __builtin_amdgcn_fdot2(__builtin_bit_cast(half2v, a),
                                __builtin_bit_cast(half2v, b), c, false);
#else
  half2v av = __builtin_bit_cast(half2v, a), bv = __builtin_bit_cast(half2v, b);
  return c + (float)av.x * (float)bv.x + (float)av.y * (float)bv.y;
#endif
}

static __device__ __forceinline__ float sig_(float x) {
  return 1.0f / (1.0f + __expf(-x));
}
static __device__ __forceinline__ float tanh_(float x) {
  float ax = fminf(fabsf(x), 15.0f);
  float e  = __expf(2.0f * ax);
  float t  = (e - 1.0f) / (e + 1.0f);
  return copysignf(t, x);
}

// ---------------- small prep kernels ----------------

__global__ void cvt_f16(const float* __restrict__ in, u16* __restrict__ out, int n) {
  int i = blockIdx.x * blockDim.x + threadIdx.x;
  if (i < n) out[i] = __builtin_bit_cast(u16, (f16)in[i]);
}

__global__ void split_w(const float* __restrict__ w, u16* __restrict__ hi,
                        u16* __restrict__ lo, int n) {
  int i = blockIdx.x * blockDim.x + threadIdx.x;
  if (i < n) {
    float v = w[i];
    f16 h = (f16)v;
    float r = v - (float)h;
    hi[i] = __builtin_bit_cast(u16, h);
    lo[i] = __builtin_bit_cast(u16, (f16)r);
  }
}

__global__ void bias_sum(const float* __restrict__ a, const float* __restrict__ b,
                         float* __restrict__ o, int n) {
  int i = blockIdx.x * blockDim.x + threadIdx.x;
  if (i < n) o[i] = a[i] + b[i];
}

// ---------------- f16 MFMA GEMM with weight hi/lo split ----------------
template<int BN>
__global__ __launch_bounds__(256) void gemm_ws(
    const u16* __restrict__ A, const u16* __restrict__ Bh, const u16* __restrict__ Bl,
    const float* __restrict__ bias, float* __restrict__ C,
    int K, int tcl, int t0, int N)
{
  constexpr int BM = 128, BK = 64, LDT = 72;
  __shared__ u16 As[BM * LDT];
  __shared__ u16 Bhs[BN * LDT];
  __shared__ u16 Bls[BN * LDT];
  const int tid = threadIdx.x, wave = tid >> 6, lane = tid & 63;
  const int m0 = blockIdx.x * BM, n0 = blockIdx.y * BN;
  constexpr int WNT = BN / 32;
  const int wm0 = (wave >> 1) * 64, wn0 = (wave & 1) * (BN / 2);
  const int tcmask = (1 << tcl) - 1;
  float4v acc[4][WNT];
  for (int i = 0; i < 4; i++)
    for (int j = 0; j < WNT; j++) acc[i][j] = (float4v){0.f, 0.f, 0.f, 0.f};
  const int lrow = lane & 15, lk = (lane >> 4) * 8;

  for (int k0 = 0; k0 < K; k0 += BK) {
    __syncthreads();
#pragma unroll
    for (int i = 0; i < 4; i++) {
      int idx = tid + i * 256, row = idx >> 3, u = idx & 7;
      int m = m0 + row;
      int rg = (m >> tcl) * T_ + t0 + (m & tcmask);
      *(uint4*)(As + row * LDT + u * 8) =
          *(const uint4*)(A + (size_t)rg * K + k0 + u * 8);
    }
#pragma unroll
    for (int i = 0; i < WNT; i++) {
      int idx = tid + i * 256, row = idx >> 3, u = idx & 7;
      size_t go = (size_t)(n0 + row) * K + k0 + u * 8;
      *(uint4*)(Bhs + row * LDT + u * 8) = *(const uint4*)(Bh + go);
      *(uint4*)(Bls + row * LDT + u * 8) = *(const uint4*)(Bl + go);
    }
    __syncthreads();
#pragma unroll
    for (int ks = 0; ks < 2; ++ks) {
      int col = ks * 32 + lk;
      half8v af[4];
#pragma unroll
      for (int mt = 0; mt < 4; mt++)
        af[mt] = *(const half8v*)(const void*)(As + (wm0 + mt * 16 + lrow) * LDT + col);
#pragma unroll
      for (int nt = 0; nt < WNT; nt++) {
        half8v bhv = *(const half8v*)(const void*)(Bhs + (wn0 + nt * 16 + lrow) * LDT + col);
        half8v blv = *(const half8v*)(const void*)(Bls + (wn0 + nt * 16 + lrow) * LDT + col);
#pragma unroll
        for (int mt = 0; mt < 4; mt++) {
          acc[mt][nt] = __builtin_amdgcn_mfma_f32_16x16x32_f16(af[mt], bhv, acc[mt][nt], 0, 0, 0);
          acc[mt][nt] = __builtin_amdgcn_mfma_f32_16x16x32_f16(af[mt], blv, acc[mt][nt], 0, 0, 0);
        }
      }
    }
  }
  const int crow = (lane >> 4) * 4, ccol = lane & 15;
#pragma unroll
  for (int nt = 0; nt < WNT; nt++) {
    int n = n0 + wn0 + nt * 16 + ccol;
    float bv = bias[n];
#pragma unroll
    for (int mt = 0; mt < 4; mt++) {
#pragma unroll
      for (int r = 0; r < 4; r++) {
        int m = m0 + wm0 + mt * 16 + crow + r;
        C[(size_t)m * N + n] = acc[mt][nt][r] + bv;
      }
    }
  }
}

// ---------------- persistent per-batch LSTM scan ----------------
// One block per batch element, 512 threads = 8 waves, 1 block/CU (129 KB LDS).
// Lane L of wave w owns hidden unit u = w*32 + (L&31); lanes L<32 own gate
// rows {i,g} of u, lanes L>=32 own {f,o}.
// Weight cols [0,192) for both rows = 48 quads PINNED IN AGPRS via inline asm
// (the compiler spilled these to scratch in every prior attempt). Cols
// [192,256) in LDS (128 KB). h cols [0,128): one ds_read_b32 gather + 64
// v_readlane -> uniform operand of v_dot2 (moves broadcast off the LDS pipe);
// h cols [128,256): LDS b128 broadcast. ONE barrier per step; gate exchange
// via __shfl_xor(32).
__global__ __launch_bounds__(512) void lstm_scan(
    const u16* __restrict__ whh, const float* __restrict__ xp,
    u16* __restrict__ hout, float* __restrict__ cst, u16* __restrict__ hst,
    int Tc, int t0)
{
  __shared__ u16 wt[8 * 1024 * 8];   // 128 KB tail: chunk q of row r at (q*1024+r)*16B
  __shared__ u32 hbuf[2][128];       // h as 256 packed f16, double buffered
  const int tid = threadIdx.x, b = blockIdx.x;
  const int lane = tid & 63, wv = tid >> 6;
  const int u = wv * 32 + (lane & 31);   // hidden unit
  const int g0 = lane >> 5;              // 0 -> rows {i,g}; 1 -> rows {f,o}
  const int r0 = g0 * 256 + u;           // i or f row
  const int r1 = (g0 + 2) * 256 + u;     // g or o row

  // ---- load weights: quads 0..23 of each row (cols 0..192) into AGPRs ----
  float4v wA[48];
  {
    const uint4* gp0 = (const uint4*)(whh + (size_t)r0 * 256);
    const uint4* gp1 = (const uint4*)(whh + (size_t)r1 * 256);
#pragma unroll
    for (int i = 0; i < 24; i++) {
      uint4 q0 = gp0[i], q1 = gp1[i];
      AG_PIN(wA[i],      __builtin_bit_cast(float4v, q0));
      AG_PIN(wA[24 + i], __builtin_bit_cast(float4v, q1));
    }
#pragma unroll
    for (int q = 0; q < 8; q++) {
      *(uint4*)(wt + (size_t)(q * 1024 + r0) * 8) = gp0[24 + q];
      *(uint4*)(wt + (size_t)(q * 1024 + r1) * 8) = gp1[24 + q];
    }
  }

  float cc = 0.f;
  if (t0 == 0) {
    if (tid < 128) hbuf[0][tid] = 0u;
  } else {
    cc = cst[(size_t)b * 256 + u];
    if (tid < 128) hbuf[0][tid] = ((const u32*)hst)[(size_t)b * 128 + tid];
  }
  __syncthreads();

  const float* xpb = xp + (size_t)b * Tc * 1024;
  float xn0 = xpb[r0], xn1 = xpb[r1];
  u16* houtb = hout + ((size_t)b * T_ + t0) * 256;

  u16 hb = 0;
  for (int tt = 0; tt < Tc; ++tt) {
    float a0 = xn0, a1 = xn1;
    if (tt + 1 < Tc) {
      xn0 = xpb[(size_t)(tt + 1) * 1024 + r0];
      xn1 = xpb[(size_t)(tt + 1) * 1024 + r1];
    }
    const u32* hcur = hbuf[tt & 1];
    // gather: lane l holds h dword l (l<64 -> h cols [0,128))
    u32 hg = hcur[lane];
    const uint4* hq = (const uint4*)hcur;

    // cols [0,128): weights from AGPR, h uniform via readlane
#pragma unroll
    for (int kc = 0; kc < 16; ++kc) {
      float4v q0, q1;
      AG_GET(q0, wA[kc]);
      AG_GET(q1, wA[24 + kc]);
      uint4 w0 = __builtin_bit_cast(uint4, q0);
      uint4 w1 = __builtin_bit_cast(uint4, q1);
      u32 h0 = __builtin_amdgcn_readlane(hg, 4 * kc + 0);
      u32 h1 = __builtin_amdgcn_readlane(hg, 4 * kc + 1);
      u32 h2 = __builtin_amdgcn_readlane(hg, 4 * kc + 2);
      u32 h3 = __builtin_amdgcn_readlane(hg, 4 * kc + 3);
      a0 = fdot2u(w0.x, h0, a0); a0 = fdot2u(w0.y, h1, a0);
      a0 = fdot2u(w0.z, h2, a0); a0 = fdot2u(w0.w, h3, a0);
      a1 = fdot2u(w1.x, h0, a1); a1 = fdot2u(w1.y, h1, a1);
      a1 = fdot2u(w1.z, h2, a1); a1 = fdot2u(w1.w, h3, a1);
    }
    // cols [128,192): weights from AGPR, h via LDS broadcast
#pragma unroll
    for (int kc = 16; kc < 24; ++kc) {
      float4v q0, q1;
      AG_GET(q0, wA[kc]);
      AG_GET(q1, wA[24 + kc]);
      uint4 w0 = __builtin_bit_cast(uint4, q0);
      uint4 w1 = __builtin_bit_cast(uint4, q1);
      uint4 hv = hq[kc];
      a0 = fdot2u(w0.x, hv.x, a0); a0 = fdot2u(w0.y, hv.y, a0);
      a0 = fdot2u(w0.z, hv.z, a0); a0 = fdot2u(w0.w, hv.w, a0);
      a1 = fdot2u(w1.x, hv.x, a1); a1 = fdot2u(w1.y, hv.y, a1);
      a1 = fdot2u(w1.z, hv.z, a1); a1 = fdot2u(w1.w, hv.w, a1);
    }
    // cols [192,256): weights from LDS, h via LDS broadcast
#pragma unroll
    for (int q = 0; q < 8; ++q) {
      uint4 hv = hq[24 + q];
      uint4 t0v = *(const uint4*)(wt + (size_t)(q * 1024 + r0) * 8);
      uint4 t1v = *(const uint4*)(wt + (size_t)(q * 1024 + r1) * 8);
      a0 = fdot2u(t0v.x, hv.x, a0); a0 = fdot2u(t0v.y, hv.y, a0);
      a0 = fdot2u(t0v.z, hv.z, a0); a0 = fdot2u(t0v.w, hv.w, a0);
      a1 = fdot2u(t1v.x, hv.x, a1); a1 = fdot2u(t1v.y, hv.y, a1);
      a1 = fdot2u(t1v.z, hv.z, a1); a1 = fdot2u(t1v.w, hv.w, a1);
    }
    // exchange between lane pair (L, L^32): L<32 has (i,g), L>=32 has (f,o)
    float b0 = __shfl_xor(a0, 32);
    float b1 = __shfl_xor(a1, 32);
    float ipre = g0 ? b0 : a0;
    float fpre = g0 ? a0 : b0;
    float gpre = g0 ? b1 : a1;
    float opre = g0 ? a1 : b1;
    float iv = sig_(ipre), fv = sig_(fpre), gv = tanh_(gpre), ov = sig_(opre);
    cc = fv * cc + iv * gv;
    float hval = ov * tanh_(cc);
    hb = __builtin_bit_cast(u16, (f16)hval);
    if (g0 == 0) {
      ((u16*)hbuf[(tt + 1) & 1])[u] = hb;
      houtb[(size_t)tt * 256 + u] = hb;
    }
    __syncthreads();
  }
  if (g0 == 0) {
    cst[(size_t)b * 256 + u] = cc;
    hst[(size_t)b * 256 + u] = hb;
  }
}

// ---------------- host ----------------

extern "C" void kernel_launch(void* const* d_in, const int* in_sizes, int n_in,
                              void* d_out, int out_size, void* d_ws, size_t ws_size,
                              hipStream_t stream)
{
  const float* x      = (const float*)d_in[0];
  const float* Wih[4] = {(const float*)d_in[1], (const float*)d_in[5],
                         (const float*)d_in[9], (const float*)d_in[13]};
  const float* Whh[4] = {(const float*)d_in[2], (const float*)d_in[6],
                         (const float*)d_in[10], (const float*)d_in[14]};
  const float* bi[4]  = {(const float*)d_in[3], (const float*)d_in[7],
                         (const float*)d_in[11], (const float*)d_in[15]};
  const float* bh[4]  = {(const float*)d_in[4], (const float*)d_in[8],
                         (const float*)d_in[12], (const float*)d_in[16]};
  const float* outW   = (const float*)d_in[17];
  const float* outb   = (const float*)d_in[18];

  char* ws = (char*)d_ws;
  size_t off = 0;
  auto alc = [&](size_t bytes) -> char* {
    char* p = ws + off;
    off = (off + bytes + 255) & ~(size_t)255;
    return p;
  };

  u16* xf  = (u16*)alc((size_t)BT_ * I_ * 2);
  u16* hb0 = (u16*)alc((size_t)BT_ * H_ * 2);
  u16* hb1 = (u16*)alc((size_t)BT_ * H_ * 2);
  int wihn[4] = {G_ * I_, G_ * H_, G_ * H_, G_ * H_};
  u16 *wihH[4], *wihL[4], *whhH[4];
  float* bsum[4];
  for (int l = 0; l < 4; l++) {
    wihH[l] = (u16*)alc((size_t)wihn[l] * 2);
    wihL[l] = (u16*)alc((size_t)wihn[l] * 2);
    whhH[l] = (u16*)alc((size_t)G_ * H_ * 2);
    bsum[l] = (float*)alc((size_t)G_ * 4);
  }
  u16* owH = (u16*)alc((size_t)I_ * H_ * 2);
  u16* owL = (u16*)alc((size_t)I_ * H_ * 2);
  float* cst = (float*)alc((size_t)B_ * H_ * 4);
  u16*   hst = (u16*)alc((size_t)B_ * H_ * 2);

  int Tc = T_;
  while (Tc > 16 && off + (size_t)B_ * Tc * G_ * 4 + 4096 > ws_size) Tc >>= 1;
  float* xpb = (float*)alc((size_t)B_ * Tc * G_ * 4);
  int tcl = 0;
  while ((1 << tcl) < Tc) tcl++;

  {
    int n = BT_ * I_;
    cvt_f16<<<dim3((n + 255) / 256), dim3(256), 0, stream>>>(x, xf, n);
  }
  for (int l = 0; l < 4; l++) {
    split_w<<<dim3((wihn[l] + 255) / 256), dim3(256), 0, stream>>>(Wih[l], wihH[l], wihL[l], wihn[l]);
    cvt_f16<<<dim3((G_ * H_ + 255) / 256), dim3(256), 0, stream>>>(Whh[l], whhH[l], G_ * H_);
    bias_sum<<<dim3(4), dim3(256), 0, stream>>>(bi[l], bh[l], bsum[l], G_);
  }
  split_w<<<dim3((I_ * H_ + 255) / 256), dim3(256), 0, stream>>>(outW, owH, owL, I_ * H_);

  for (int l = 0; l < 4; l++) {
    const u16* Ain = (l == 0) ? xf : ((l == 1) ? hb0 : (l == 2) ? hb1 : hb0);
    u16* Hout = (l & 1) ? hb1 : hb0;
    int K = (l == 0) ? I_ : H_;
    for (int t0 = 0; t0 < T_; t0 += Tc) {
      gemm_ws<128><<<dim3((B_ * Tc) / 128, G_ / 128), dim3(256), 0, stream>>>(
          Ain, wihH[l], wihL[l], bsum[l], xpb, K, tcl, t0, G_);
      lstm_scan<<<dim3(B_), dim3(512), 0, stream>>>(whhH[l], xpb, Hout, cst, hst, Tc, t0);
    }
  }

  gemm_ws<64><<<dim3(BT_ / 128, 1), dim3(256), 0, stream>>>(
      hb1, owH, owL, outb, (float*)d_out, H_, 9, 0, I_);
}

// Round 5
// 5648.392 us; speedup vs baseline: 1.3632x; 1.3632x over previous
//
#include <hip/hip_runtime.h>

typedef unsigned short u16;
typedef unsigned int   u32;
typedef _Float16 f16;
typedef _Float16 half2v __attribute__((ext_vector_type(2)));
typedef _Float16 half8v __attribute__((ext_vector_type(8)));
typedef float float4v __attribute__((ext_vector_type(4)));

#define B_  256
#define T_  512
#define I_  64
#define H_  256
#define G_  1024   // 4*H
#define BT_ (B_*T_)

static __device__ __forceinline__ float fdot2u(u32 a, u32 b, float c) {
#if defined(__has_builtin) && __has_builtin(__builtin_amdgcn_fdot2)
  return __builtin_amdgcn_fdot2(__builtin_bit_cast(half2v, a),
                                __builtin_bit_cast(half2v, b), c, false);
#else
  half2v av = __builtin_bit_cast(half2v, a), bv = __builtin_bit_cast(half2v, b);
  return c + (float)av.x * (float)bv.x + (float)av.y * (float)bv.y;
#endif
}

static __device__ __forceinline__ float sig_(float x) {
  return 1.0f / (1.0f + __expf(-x));
}
static __device__ __forceinline__ float tanh_(float x) {
  float ax = fminf(fabsf(x), 15.0f);
  float e  = __expf(2.0f * ax);
  float t  = (e - 1.0f) / (e + 1.0f);
  return copysignf(t, x);
}

// ---------------- small prep kernels ----------------

__global__ void cvt_f16(const float* __restrict__ in, u16* __restrict__ out, int n) {
  int i = blockIdx.x * blockDim.x + threadIdx.x;
  if (i < n) out[i] = __builtin_bit_cast(u16, (f16)in[i]);
}

__global__ void split_w(const float* __restrict__ w, u16* __restrict__ hi,
                        u16* __restrict__ lo, int n) {
  int i = blockIdx.x * blockDim.x + threadIdx.x;
  if (i < n) {
    float v = w[i];
    f16 h = (f16)v;
    float r = v - (float)h;
    hi[i] = __builtin_bit_cast(u16, h);
    lo[i] = __builtin_bit_cast(u16, (f16)r);
  }
}

__global__ void bias_sum(const float* __restrict__ a, const float* __restrict__ b,
                         float* __restrict__ o, int n) {
  int i = blockIdx.x * blockDim.x + threadIdx.x;
  if (i < n) o[i] = a[i] + b[i];
}

// ---------------- f16 MFMA GEMM with weight hi/lo split ----------------
template<int BN>
__global__ __launch_bounds__(256) void gemm_ws(
    const u16* __restrict__ A, const u16* __restrict__ Bh, const u16* __restrict__ Bl,
    const float* __restrict__ bias, float* __restrict__ C,
    int K, int tcl, int t0, int N)
{
  constexpr int BM = 128, BK = 64, LDT = 72;
  __shared__ u16 As[BM * LDT];
  __shared__ u16 Bhs[BN * LDT];
  __shared__ u16 Bls[BN * LDT];
  const int tid = threadIdx.x, wave = tid >> 6, lane = tid & 63;
  const int m0 = blockIdx.x * BM, n0 = blockIdx.y * BN;
  constexpr int WNT = BN / 32;
  const int wm0 = (wave >> 1) * 64, wn0 = (wave & 1) * (BN / 2);
  const int tcmask = (1 << tcl) - 1;
  float4v acc[4][WNT];
  for (int i = 0; i < 4; i++)
    for (int j = 0; j < WNT; j++) acc[i][j] = (float4v){0.f, 0.f, 0.f, 0.f};
  const int lrow = lane & 15, lk = (lane >> 4) * 8;

  for (int k0 = 0; k0 < K; k0 += BK) {
    __syncthreads();
#pragma unroll
    for (int i = 0; i < 4; i++) {
      int idx = tid + i * 256, row = idx >> 3, u = idx & 7;
      int m = m0 + row;
      int rg = (m >> tcl) * T_ + t0 + (m & tcmask);
      *(uint4*)(As + row * LDT + u * 8) =
          *(const uint4*)(A + (size_t)rg * K + k0 + u * 8);
    }
#pragma unroll
    for (int i = 0; i < WNT; i++) {
      int idx = tid + i * 256, row = idx >> 3, u = idx & 7;
      size_t go = (size_t)(n0 + row) * K + k0 + u * 8;
      *(uint4*)(Bhs + row * LDT + u * 8) = *(const uint4*)(Bh + go);
      *(uint4*)(Bls + row * LDT + u * 8) = *(const uint4*)(Bl + go);
    }
    __syncthreads();
#pragma unroll
    for (int ks = 0; ks < 2; ++ks) {
      int col = ks * 32 + lk;
      half8v af[4];
#pragma unroll
      for (int mt = 0; mt < 4; mt++)
        af[mt] = *(const half8v*)(const void*)(As + (wm0 + mt * 16 + lrow) * LDT + col);
#pragma unroll
      for (int nt = 0; nt < WNT; nt++) {
        half8v bhv = *(const half8v*)(const void*)(Bhs + (wn0 + nt * 16 + lrow) * LDT + col);
        half8v blv = *(const half8v*)(const void*)(Bls + (wn0 + nt * 16 + lrow) * LDT + col);
#pragma unroll
        for (int mt = 0; mt < 4; mt++) {
          acc[mt][nt] = __builtin_amdgcn_mfma_f32_16x16x32_f16(af[mt], bhv, acc[mt][nt], 0, 0, 0);
          acc[mt][nt] = __builtin_amdgcn_mfma_f32_16x16x32_f16(af[mt], blv, acc[mt][nt], 0, 0, 0);
        }
      }
    }
  }
  const int crow = (lane >> 4) * 4, ccol = lane & 15;
#pragma unroll
  for (int nt = 0; nt < WNT; nt++) {
    int n = n0 + wn0 + nt * 16 + ccol;
    float bv = bias[n];
#pragma unroll
    for (int mt = 0; mt < 4; mt++) {
#pragma unroll
      for (int r = 0; r < 4; r++) {
        int m = m0 + wm0 + mt * 16 + crow + r;
        C[(size_t)m * N + n] = acc[mt][nt][r] + bv;
      }
    }
  }
}

// ---------------- persistent per-batch LSTM scan (v3) ----------------
// One block per batch element, 512 threads = 8 waves, 1 block/CU (145 KB LDS).
// NO __launch_bounds__ -- occupancy pinned ONLY via amdgpu_waves_per_eu(2,2)
// (2 waves/EU -> 256-VGPR budget; launch_bounds' implied attributes clobbered
// this in every prior round, leaving the default 4 waves/EU -> 128 regs ->
// weights spilled to scratch).
// Lane L of wave w owns hidden unit u = w*32+(L&31); L<32 -> gate rows {i,g},
// L>=32 -> {f,o}. Weight cols [0,184) of both rows in registers (46 quads,
// 184 VGPRs); cols [184,256) in LDS (9 quads/row, 144 KB, [quad][row] layout
// -> wave reads contiguous 16B slots, conflict-free).
// h distributed via 2 ds_read_b32 + v_readlane (SGPR operand of v_dot2),
// replacing 32 broadcast b128 LDS reads/thread -- LDS instr/step/thread
// drops 48 -> 21. ONE barrier per step; gate exchange via __shfl_xor(32).
__global__ __attribute__((amdgpu_flat_work_group_size(512, 512),
                          amdgpu_waves_per_eu(2, 2)))
void lstm_scan(
    const u16* __restrict__ whh, const float* __restrict__ xp,
    u16* __restrict__ hout, float* __restrict__ cst, u16* __restrict__ hst,
    int Tc, int t0)
{
  __shared__ u16 wt[9 * 1024 * 8];   // 144 KB tail: quad q (of 9) of row r at ((q*1024+r)*8) u16s
  __shared__ u32 hbuf[2][128];       // h as 256 packed f16, double buffered
  const int tid = threadIdx.x, b = blockIdx.x;
  const int lane = tid & 63, wv = tid >> 6;
  const int u = wv * 32 + (lane & 31);   // hidden unit
  const int g0 = lane >> 5;              // 0 -> rows {i,g}; 1 -> rows {f,o}
  const int r0 = g0 * 256 + u;           // i or f row
  const int r1 = (g0 + 2) * 256 + u;     // g or o row

  // stage LDS tail (cols 184..256) and init h/c state
  {
    const uint4* gp0 = (const uint4*)(whh + (size_t)r0 * 256);
    const uint4* gp1 = (const uint4*)(whh + (size_t)r1 * 256);
#pragma unroll
    for (int q = 0; q < 9; q++) {
      *(uint4*)(wt + (q * 1024 + r0) * 8) = gp0[23 + q];
      *(uint4*)(wt + (q * 1024 + r1) * 8) = gp1[23 + q];
    }
  }
  float cc = 0.f;
  if (t0 == 0) {
    if (tid < 128) hbuf[0][tid] = 0u;
  } else {
    cc = cst[b * 256 + u];
    if (tid < 128) hbuf[0][tid] = ((const u32*)hst)[b * 128 + tid];
  }

  // register-resident weights: quads 0..22 of each row (cols 0..184)
  uint4 wr0[23], wr1[23];
  {
    const uint4* gp0 = (const uint4*)(whh + (size_t)r0 * 256);
    const uint4* gp1 = (const uint4*)(whh + (size_t)r1 * 256);
#pragma unroll
    for (int i = 0; i < 23; i++) { wr0[i] = gp0[i]; wr1[i] = gp1[i]; }
  }
  __syncthreads();

  const float* xpb = xp + (size_t)b * Tc * 1024;
  float xn0 = xpb[r0], xn1 = xpb[r1];
  u16* houtb = hout + ((size_t)b * T_ + t0) * 256;

  u16 hb = 0;
#pragma clang loop unroll(disable)
  for (int tt = 0; tt < Tc; ++tt) {
    float a0 = xn0, a1 = xn1;
    {
      int ttn = (tt + 1 < Tc) ? (tt + 1) : tt;   // branchless prefetch index
      xn0 = xpb[ttn * 1024 + r0];
      xn1 = xpb[ttn * 1024 + r1];
    }
    const u32* hcur = hbuf[tt & 1];
    u32 hg0 = hcur[lane];        // h dwords [0,64)
    u32 hg1 = hcur[64 + lane];   // h dwords [64,128)

#pragma unroll
    for (int qi = 0; qi < 32; ++qi) {
      u32 h0, h1, h2, h3;
      if (qi < 16) {
        h0 = __builtin_amdgcn_readlane(hg0, 4 * qi + 0);
        h1 = __builtin_amdgcn_readlane(hg0, 4 * qi + 1);
        h2 = __builtin_amdgcn_readlane(hg0, 4 * qi + 2);
        h3 = __builtin_amdgcn_readlane(hg0, 4 * qi + 3);
      } else {
        h0 = __builtin_amdgcn_readlane(hg1, 4 * qi - 64);
        h1 = __builtin_amdgcn_readlane(hg1, 4 * qi - 63);
        h2 = __builtin_amdgcn_readlane(hg1, 4 * qi - 62);
        h3 = __builtin_amdgcn_readlane(hg1, 4 * qi - 61);
      }
      uint4 w0, w1;
      if (qi < 23) {
        w0 = wr0[qi];
        w1 = wr1[qi];
      } else {
        w0 = *(const uint4*)(wt + ((qi - 23) * 1024 + r0) * 8);
        w1 = *(const uint4*)(wt + ((qi - 23) * 1024 + r1) * 8);
      }
      a0 = fdot2u(w0.x, h0, a0); a0 = fdot2u(w0.y, h1, a0);
      a0 = fdot2u(w0.z, h2, a0); a0 = fdot2u(w0.w, h3, a0);
      a1 = fdot2u(w1.x, h0, a1); a1 = fdot2u(w1.y, h1, a1);
      a1 = fdot2u(w1.z, h2, a1); a1 = fdot2u(w1.w, h3, a1);
    }
    // exchange between lane pair (L, L^32): L<32 has (i,g), L>=32 has (f,o)
    float b0 = __shfl_xor(a0, 32);
    float b1 = __shfl_xor(a1, 32);
    float ipre = g0 ? b0 : a0;
    float fpre = g0 ? a0 : b0;
    float gpre = g0 ? b1 : a1;
    float opre = g0 ? a1 : b1;
    float iv = sig_(ipre), fv = sig_(fpre), gv = tanh_(gpre), ov = sig_(opre);
    cc = fv * cc + iv * gv;
    float hval = ov * tanh_(cc);
    hb = __builtin_bit_cast(u16, (f16)hval);
    if (g0 == 0) {
      ((u16*)hbuf[(tt + 1) & 1])[u] = hb;
      houtb[tt * 256 + u] = hb;
    }
    __syncthreads();
  }
  if (g0 == 0) {
    cst[b * 256 + u] = cc;
    hst[b * 256 + u] = hb;
  }
}

// ---------------- host ----------------

extern "C" void kernel_launch(void* const* d_in, const int* in_sizes, int n_in,
                              void* d_out, int out_size, void* d_ws, size_t ws_size,
                              hipStream_t stream)
{
  const float* x      = (const float*)d_in[0];
  const float* Wih[4] = {(const float*)d_in[1], (const float*)d_in[5],
                         (const float*)d_in[9], (const float*)d_in[13]};
  const float* Whh[4] = {(const float*)d_in[2], (const float*)d_in[6],
                         (const float*)d_in[10], (const float*)d_in[14]};
  const float* bi[4]  = {(const float*)d_in[3], (const float*)d_in[7],
                         (const float*)d_in[11], (const float*)d_in[15]};
  const float* bh[4]  = {(const float*)d_in[4], (const float*)d_in[8],
                         (const float*)d_in[12], (const float*)d_in[16]};
  const float* outW   = (const float*)d_in[17];
  const float* outb   = (const float*)d_in[18];

  char* ws = (char*)d_ws;
  size_t off = 0;
  auto alc = [&](size_t bytes) -> char* {
    char* p = ws + off;
    off = (off + bytes + 255) & ~(size_t)255;
    return p;
  };

  u16* xf  = (u16*)alc((size_t)BT_ * I_ * 2);
  u16* hb0 = (u16*)alc((size_t)BT_ * H_ * 2);
  u16* hb1 = (u16*)alc((size_t)BT_ * H_ * 2);
  int wihn[4] = {G_ * I_, G_ * H_, G_ * H_, G_ * H_};
  u16 *wihH[4], *wihL[4], *whhH[4];
  float* bsum[4];
  for (int l = 0; l < 4; l++) {
    wihH[l] = (u16*)alc((size_t)wihn[l] * 2);
    wihL[l] = (u16*)alc((size_t)wihn[l] * 2);
    whhH[l] = (u16*)alc((size_t)G_ * H_ * 2);
    bsum[l] = (float*)alc((size_t)G_ * 4);
  }
  u16* owH = (u16*)alc((size_t)I_ * H_ * 2);
  u16* owL = (u16*)alc((size_t)I_ * H_ * 2);
  float* cst = (float*)alc((size_t)B_ * H_ * 4);
  u16*   hst = (u16*)alc((size_t)B_ * H_ * 2);

  int Tc = T_;
  while (Tc > 16 && off + (size_t)B_ * Tc * G_ * 4 + 4096 > ws_size) Tc >>= 1;
  float* xpb = (float*)alc((size_t)B_ * Tc * G_ * 4);
  int tcl = 0;
  while ((1 << tcl) < Tc) tcl++;

  {
    int n = BT_ * I_;
    cvt_f16<<<dim3((n + 255) / 256), dim3(256), 0, stream>>>(x, xf, n);
  }
  for (int l = 0; l < 4; l++) {
    split_w<<<dim3((wihn[l] + 255) / 256), dim3(256), 0, stream>>>(Wih[l], wihH[l], wihL[l], wihn[l]);
    cvt_f16<<<dim3((G_ * H_ + 255) / 256), dim3(256), 0, stream>>>(Whh[l], whhH[l], G_ * H_);
    bias_sum<<<dim3(4), dim3(256), 0, stream>>>(bi[l], bh[l], bsum[l], G_);
  }
  split_w<<<dim3((I_ * H_ + 255) / 256), dim3(256), 0, stream>>>(outW, owH, owL, I_ * H_);

  for (int l = 0; l < 4; l++) {
    const u16* Ain = (l == 0) ? xf : ((l == 1) ? hb0 : (l == 2) ? hb1 : hb0);
    u16* Hout = (l & 1) ? hb1 : hb0;
    int K = (l == 0) ? I_ : H_;
    for (int t0 = 0; t0 < T_; t0 += Tc) {
      gemm_ws<128><<<dim3((B_ * Tc) / 128, G_ / 128), dim3(256), 0, stream>>>(
          Ain, wihH[l], wihL[l], bsum[l], xpb, K, tcl, t0, G_);
      lstm_scan<<<dim3(B_), dim3(512), 0, stream>>>(whhH[l], xpb, Hout, cst, hst, Tc, t0);
    }
  }

  gemm_ws<64><<<dim3(BT_ / 128, 1), dim3(256), 0, stream>>>(
      hb1, owH, owL, outb, (float*)d_out, H_, 9, 0, I_);
}